// Round 1
// baseline (2534.694 us; speedup 1.0000x reference)
//
#include <hip/hip_runtime.h>
#include <cfloat>
#include <math.h>

constexpr int B_ = 8, N_ = 4096, S_ = 1024, NS_ = 32;
constexpr int R_ = B_ * S_ * NS_;          // 262144 rows (b,s,k)
constexpr float EPS_ = 1e-5f;

// ---------------------------------------------------------------- FPS
// One block per batch, 512 threads, 8 points each. Exact reference
// semantics: ct_idx[0]=0; dist=min(dist,d); argmax with first-index tie.
__global__ __launch_bounds__(512) void fps_kernel(const float* __restrict__ xyz,
                                                  int* __restrict__ ct_idx) {
    int b = blockIdx.x;
    const float* xb = xyz + (size_t)b * 3 * N_;
    int t = threadIdx.x;
    float px[8], py[8], pz[8], dist[8];
#pragma unroll
    for (int j = 0; j < 8; j++) {
        int n = j * 512 + t;
        px[j] = xb[n];
        py[j] = xb[N_ + n];
        pz[j] = xb[2 * N_ + n];
        dist[j] = 1e10f;
    }
    __shared__ float sv[8], sx[8], sy[8], sz[8];
    __shared__ int si[8];
    float cx = xb[0], cy = xb[N_], cz = xb[2 * N_];
    int far = 0;
    for (int it = 0; it < S_; it++) {
        if (t == 0) ct_idx[b * S_ + it] = far;
        float bv = -1.f; int bi = 0; float bx = 0.f, by = 0.f, bz = 0.f;
#pragma unroll
        for (int j = 0; j < 8; j++) {
            float dx = px[j] - cx, dy = py[j] - cy, dz = pz[j] - cz;
            float d = dx * dx + dy * dy + dz * dz;
            dist[j] = fminf(dist[j], d);
            if (dist[j] > bv) { bv = dist[j]; bi = j * 512 + t; bx = px[j]; by = py[j]; bz = pz[j]; }
        }
#pragma unroll
        for (int m = 1; m < 64; m <<= 1) {
            float ov = __shfl_xor(bv, m); int oi = __shfl_xor(bi, m);
            float ox = __shfl_xor(bx, m), oy = __shfl_xor(by, m), oz = __shfl_xor(bz, m);
            if (ov > bv || (ov == bv && oi < bi)) { bv = ov; bi = oi; bx = ox; by = oy; bz = oz; }
        }
        int w = t >> 6;
        if ((t & 63) == 0) { sv[w] = bv; si[w] = bi; sx[w] = bx; sy[w] = by; sz[w] = bz; }
        __syncthreads();
        bv = sv[0]; bi = si[0]; bx = sx[0]; by = sy[0]; bz = sz[0];
#pragma unroll
        for (int w2 = 1; w2 < 8; w2++) {
            float ov = sv[w2]; int oi = si[w2];
            if (ov > bv || (ov == bv && oi < bi)) { bv = ov; bi = oi; bx = sx[w2]; by = sy[w2]; bz = sz[w2]; }
        }
        far = bi; cx = bx; cy = by; cz = bz;
        __syncthreads();
    }
}

// ---------------------------------------------------------------- kNN
// One block per (b,s): d2 to all 4096 points in registers (16/thread),
// 32 iterations of block-argmin with smaller-index tie-break (= lax.top_k set).
__global__ __launch_bounds__(256) void knn_kernel(const float* __restrict__ xyz,
                                                  const int* __restrict__ ct_idx,
                                                  int* __restrict__ gidx) {
    int bs = blockIdx.x;
    int b = bs >> 10;
    const float* xb = xyz + (size_t)b * 3 * N_;
    int ci = ct_idx[bs];
    float cx = xb[ci], cy = xb[N_ + ci], cz = xb[2 * N_ + ci];
    float cs = cx * cx + cy * cy + cz * cz;
    int t = threadIdx.x;
    float val[16];
#pragma unroll
    for (int j = 0; j < 16; j++) {
        int n = j * 256 + t;
        float x = xb[n], y = xb[N_ + n], z = xb[2 * N_ + n];
        float xn = x * x + y * y + z * z;
        float dot = cx * x + cy * y + cz * z;
        val[j] = cs + xn - 2.f * dot;           // reference formula order
    }
    __shared__ float sv[4];
    __shared__ int si[4];
    int out_base = bs * NS_;
    for (int iter = 0; iter < NS_; iter++) {
        float bv = FLT_MAX; int bi = 1 << 30;
#pragma unroll
        for (int j = 0; j < 16; j++) {
            if (val[j] < bv) { bv = val[j]; bi = j * 256 + t; }
        }
#pragma unroll
        for (int m = 1; m < 64; m <<= 1) {
            float ov = __shfl_xor(bv, m); int oi = __shfl_xor(bi, m);
            if (ov < bv || (ov == bv && oi < bi)) { bv = ov; bi = oi; }
        }
        if ((t & 63) == 0) { sv[t >> 6] = bv; si[t >> 6] = bi; }
        __syncthreads();
        bv = sv[0]; bi = si[0];
#pragma unroll
        for (int w = 1; w < 4; w++) {
            float ov = sv[w]; int oi = si[w];
            if (ov < bv || (ov == bv && oi < bi)) { bv = ov; bi = oi; }
        }
        if (t == 0) gidx[out_base + iter] = bi;
        if ((bi & 255) == t) val[bi >> 8] = FLT_MAX;   // mark selected
        __syncthreads();
    }
}

// ---------------------------------------------------------------- ct_p output
__global__ __launch_bounds__(256) void ctp_kernel(const float* __restrict__ xyz,
                                                  const int* __restrict__ ct_idx,
                                                  float* __restrict__ out) {
    int i = blockIdx.x * 256 + threadIdx.x;
    if (i >= B_ * 3 * S_) return;
    int b = i / (3 * S_);
    int rem = i - b * 3 * S_;
    int c = rem >> 10;
    int s = rem & (S_ - 1);
    int ci = ct_idx[b * S_ + s];
    out[i] = xyz[(size_t)b * 3 * N_ + (size_t)c * N_ + ci];
}

// ---------------------------------------------------------------- gather -> ft [33][R]
// ch 0-2: rel xyz; ch 3-31: points; ch 32: rd
__global__ __launch_bounds__(256) void gather_kernel(const float* __restrict__ xyz,
                                                     const float* __restrict__ pts,
                                                     const int* __restrict__ ct_idx,
                                                     const int* __restrict__ gidx,
                                                     float* __restrict__ ft) {
    int r = blockIdx.x * 256 + threadIdx.x;
    int b = r >> 15;
    int s = (r >> 5) & (S_ - 1);
    int g = gidx[r];
    int ci = ct_idx[b * S_ + s];
    const float* xb = xyz + (size_t)b * 3 * N_;
    float rx = xb[g] - xb[ci];
    float ry = xb[N_ + g] - xb[N_ + ci];
    float rz = xb[2 * N_ + g] - xb[2 * N_ + ci];
    ft[r] = rx;
    ft[(size_t)R_ + r] = ry;
    ft[(size_t)2 * R_ + r] = rz;
    float rd = sqrtf(fmaxf(rx * rx + ry * ry + rz * rz, 1e-12f));
    ft[(size_t)32 * R_ + r] = rd;
    const float* pb = pts + (size_t)b * 29 * N_;
#pragma unroll
    for (int c = 0; c < 29; c++) ft[(size_t)(3 + c) * R_ + r] = pb[(size_t)c * N_ + g];
}

// ---------------------------------------------------------------- conv1x1 (+optional input BN-affine+relu)
// 64 output channels per y-block; 2 rows per thread; weights broadcast from LDS.
template <int CIN, bool AFF>
__global__ __launch_bounds__(256) void convk(const float* __restrict__ xin,
                                             const float* __restrict__ W,
                                             const float* __restrict__ bias,
                                             const float* __restrict__ ab,
                                             float* __restrict__ out0,
                                             float* __restrict__ out1) {
    __shared__ float Ws[CIN][64];
    __shared__ float bs[64];
    __shared__ float as_[CIN], bbs[CIN];
    int oc0 = blockIdx.y * 64;
    for (int i = threadIdx.x; i < CIN * 64; i += 256) {
        int o = i & 63, c = i >> 6;
        Ws[c][o] = W[(size_t)(oc0 + o) * CIN + c];
    }
    if (threadIdx.x < 64) bs[threadIdx.x] = bias[oc0 + threadIdx.x];
    if (AFF) {
        for (int i = threadIdx.x; i < CIN; i += 256) { as_[i] = ab[i]; bbs[i] = ab[CIN + i]; }
    }
    __syncthreads();
    size_t r0 = (size_t)blockIdx.x * 512 + threadIdx.x;
    float acc0[64], acc1[64];
#pragma unroll
    for (int o = 0; o < 64; o++) { acc0[o] = 0.f; acc1[o] = 0.f; }
    for (int c = 0; c < CIN; c++) {
        float x0 = xin[(size_t)c * R_ + r0];
        float x1 = xin[(size_t)c * R_ + r0 + 256];
        if (AFF) {
            float a = as_[c], bb = bbs[c];
            x0 = fmaxf(fmaf(a, x0, bb), 0.f);
            x1 = fmaxf(fmaf(a, x1, bb), 0.f);
        }
#pragma unroll
        for (int o = 0; o < 64; o++) {
            float w = Ws[c][o];
            acc0[o] = fmaf(x0, w, acc0[o]);
            acc1[o] = fmaf(x1, w, acc1[o]);
        }
    }
    float* outp = blockIdx.y ? out1 : out0;
#pragma unroll
    for (int o = 0; o < 64; o++) {
        float bv = bs[o];
        outp[(size_t)o * R_ + r0] = acc0[o] + bv;
        outp[(size_t)o * R_ + r0 + 256] = acc1[o] + bv;
    }
}

// conv1 branch: 4 input channels = ft{0,1,2,32} (rel xyz + rd)
__global__ __launch_bounds__(256) void conv1_kernel(const float* __restrict__ ft,
                                                    const float* __restrict__ W,
                                                    const float* __restrict__ bias,
                                                    float* __restrict__ out) {
    __shared__ float Ws[4][64];
    __shared__ float bs[64];
    {
        int i = threadIdx.x;
        if (i < 256) { int o = i & 63, c = i >> 6; Ws[c][o] = W[o * 4 + c]; }
    }
    if (threadIdx.x < 64) bs[threadIdx.x] = bias[threadIdx.x];
    __syncthreads();
    size_t r0 = (size_t)blockIdx.x * 512 + threadIdx.x;
    float acc0[64], acc1[64];
#pragma unroll
    for (int o = 0; o < 64; o++) { acc0[o] = 0.f; acc1[o] = 0.f; }
    const int chs[4] = {0, 1, 2, 32};
#pragma unroll
    for (int c = 0; c < 4; c++) {
        int ch = chs[c];
        float x0 = ft[(size_t)ch * R_ + r0];
        float x1 = ft[(size_t)ch * R_ + r0 + 256];
#pragma unroll
        for (int o = 0; o < 64; o++) {
            float w = Ws[c][o];
            acc0[o] = fmaf(x0, w, acc0[o]);
            acc1[o] = fmaf(x1, w, acc1[o]);
        }
    }
#pragma unroll
    for (int o = 0; o < 64; o++) {
        float bv = bs[o];
        out[(size_t)o * R_ + r0] = acc0[o] + bv;
        out[(size_t)o * R_ + r0 + 256] = acc1[o] + bv;
    }
}

// ---------------------------------------------------------------- BN stats (deterministic 2-stage)
__global__ __launch_bounds__(256) void stats_partial(const float* __restrict__ y,
                                                     float* __restrict__ partial,
                                                     int cofs) {
    int c = blockIdx.x, p = blockIdx.y;
    const float* src = y + (size_t)c * R_ + (size_t)p * (R_ / 32);
    float s = 0.f, q = 0.f;
    for (int i = threadIdx.x; i < R_ / 32; i += 256) {
        float v = src[i];
        s += v;
        q = fmaf(v, v, q);
    }
#pragma unroll
    for (int m = 1; m < 64; m <<= 1) { s += __shfl_xor(s, m); q += __shfl_xor(q, m); }
    __shared__ float ls[4], lq[4];
    int w = threadIdx.x >> 6;
    if ((threadIdx.x & 63) == 0) { ls[w] = s; lq[w] = q; }
    __syncthreads();
    if (threadIdx.x == 0) {
        s = ls[0] + ls[1] + ls[2] + ls[3];
        q = lq[0] + lq[1] + lq[2] + lq[3];
        int idx = ((cofs + c) * 32 + p) * 2;
        partial[idx] = s;
        partial[idx + 1] = q;
    }
}

__global__ __launch_bounds__(64) void stats_final(const float* __restrict__ partial,
                                                  const float* __restrict__ g,
                                                  const float* __restrict__ be,
                                                  float* __restrict__ ab, int C) {
    int c = blockIdx.x, t = threadIdx.x;
    float s = 0.f, q = 0.f;
    if (t < 32) {
        int idx = (c * 32 + t) * 2;
        s = partial[idx];
        q = partial[idx + 1];
    }
#pragma unroll
    for (int m = 1; m < 32; m <<= 1) { s += __shfl_xor(s, m); q += __shfl_xor(q, m); }
    if (t == 0) {
        float inv = 1.0f / (float)R_;
        float mean = s * inv;
        float var = q * inv - mean * mean;
        float a = g[c] / sqrtf(var + EPS_);
        ab[c] = a;
        ab[C + c] = be[c] - mean * a;
    }
}

// ---------------------------------------------------------------- epilogues
__global__ __launch_bounds__(128) void final_max(const float* __restrict__ yA,
                                                 const float* __restrict__ yC,
                                                 const float* __restrict__ ab,
                                                 float* __restrict__ out) {
    int bs = blockIdx.x;
    int c = threadIdx.x;
    const float* src = (c < 64 ? yA + (size_t)c * R_ : yC + (size_t)(c - 64) * R_) + (size_t)bs * NS_;
    float a = ab[c], bb = ab[128 + c];
    const float4* s4 = reinterpret_cast<const float4*>(src);
    float m = -FLT_MAX;
#pragma unroll
    for (int i = 0; i < 8; i++) {
        float4 v = s4[i];
        m = fmaxf(m, fmaxf(fmaf(a, v.x, bb), 0.f));
        m = fmaxf(m, fmaxf(fmaf(a, v.y, bb), 0.f));
        m = fmaxf(m, fmaxf(fmaf(a, v.z, bb), 0.f));
        m = fmaxf(m, fmaxf(fmaf(a, v.w, bb), 0.f));
    }
    int b = bs >> 10, s = bs & (S_ - 1);
    out[24576 + (size_t)b * 393216 + (size_t)c * 1024 + s] = m;
}

__global__ __launch_bounds__(128) void final_meanmax(const float* __restrict__ z1,
                                                     const float* __restrict__ z2,
                                                     const float* __restrict__ ab1,
                                                     const float* __restrict__ ab2,
                                                     float* __restrict__ out) {
    int bs = blockIdx.x;
    int c = threadIdx.x;
    const float* src;
    float a, bb;
    if (c < 64) { src = z1 + (size_t)c * R_; a = ab1[c]; bb = ab1[64 + c]; }
    else        { src = z2 + (size_t)(c - 64) * R_; a = ab2[c - 64]; bb = ab2[64 + (c - 64)]; }
    src += (size_t)bs * NS_;
    const float4* s4 = reinterpret_cast<const float4*>(src);
    float m = -FLT_MAX, sm = 0.f;
#pragma unroll
    for (int i = 0; i < 8; i++) {
        float4 v = s4[i];
        float t0 = fmaxf(fmaf(a, v.x, bb), 0.f); sm += t0; m = fmaxf(m, t0);
        float t1 = fmaxf(fmaf(a, v.y, bb), 0.f); sm += t1; m = fmaxf(m, t1);
        float t2 = fmaxf(fmaf(a, v.z, bb), 0.f); sm += t2; m = fmaxf(m, t2);
        float t3 = fmaxf(fmaf(a, v.w, bb), 0.f); sm += t3; m = fmaxf(m, t3);
    }
    int b = bs >> 10, s = bs & (S_ - 1);
    size_t ob = 24576 + (size_t)b * 393216;
    out[ob + (size_t)(128 + c) * 1024 + s] = sm * 0.03125f;
    out[ob + (size_t)(256 + c) * 1024 + s] = m;
}

// ================================================================ launch
extern "C" void kernel_launch(void* const* d_in, const int* in_sizes, int n_in,
                              void* d_out, int out_size, void* d_ws, size_t ws_size,
                              hipStream_t stream) {
    const float* xyz = (const float*)d_in[0];
    const float* pts = (const float*)d_in[1];
    const float* W0 = (const float*)d_in[2];  const float* b0 = (const float*)d_in[3];
    const float* g0 = (const float*)d_in[4];  const float* be0 = (const float*)d_in[5];
    const float* W1 = (const float*)d_in[6];  const float* b1 = (const float*)d_in[7];
    const float* g1 = (const float*)d_in[8];  const float* be1 = (const float*)d_in[9];
    const float* W2 = (const float*)d_in[10]; const float* b2 = (const float*)d_in[11];
    const float* g2 = (const float*)d_in[12]; const float* be2 = (const float*)d_in[13];
    const float* c1w = (const float*)d_in[14]; const float* c1b = (const float*)d_in[15];
    const float* bg1 = (const float*)d_in[16]; const float* bbe1 = (const float*)d_in[17];
    const float* c2w = (const float*)d_in[18]; const float* c2b = (const float*)d_in[19];
    const float* bg2 = (const float*)d_in[20]; const float* bbe2 = (const float*)d_in[21];
    float* out = (float*)d_out;

    // workspace layout (floats after the two int arrays)
    int* ct_idx = (int*)d_ws;                       // [8192]
    int* gidx = ct_idx + B_ * S_;                   // [262144]
    float* fbase = (float*)d_ws;
    float* ft = fbase + 270336;                     // 33*R
    float* A = ft + (size_t)33 * R_;                // 64*R   (y0 -> y2.lo -> z1)
    float* Bb = A + (size_t)64 * R_;                // 64*R   (y1 -> z2)
    float* C = Bb + (size_t)64 * R_;                // 64*R   (y2.hi)
    float* partial = C + (size_t)64 * R_;           // 8192
    float* ab0 = partial + 8192;                    // 128
    float* ab1 = ab0 + 128;                         // 128
    float* ab2 = ab1 + 128;                         // 256
    float* abz1 = ab2 + 256;                        // 128
    float* abz2 = abz1 + 128;                       // 128

    fps_kernel<<<B_, 512, 0, stream>>>(xyz, ct_idx);
    knn_kernel<<<B_ * S_, 256, 0, stream>>>(xyz, ct_idx, gidx);
    ctp_kernel<<<(B_ * 3 * S_ + 255) / 256, 256, 0, stream>>>(xyz, ct_idx, out);
    gather_kernel<<<R_ / 256, 256, 0, stream>>>(xyz, pts, ct_idx, gidx, ft);

    // MLP stack
    convk<32, false><<<dim3(R_ / 512, 1), 256, 0, stream>>>(ft, W0, b0, nullptr, A, nullptr);
    stats_partial<<<dim3(64, 32), 256, 0, stream>>>(A, partial, 0);
    stats_final<<<64, 64, 0, stream>>>(partial, g0, be0, ab0, 64);
    convk<64, true><<<dim3(R_ / 512, 1), 256, 0, stream>>>(A, W1, b1, ab0, Bb, nullptr);
    stats_partial<<<dim3(64, 32), 256, 0, stream>>>(Bb, partial, 0);
    stats_final<<<64, 64, 0, stream>>>(partial, g1, be1, ab1, 64);
    convk<64, true><<<dim3(R_ / 512, 2), 256, 0, stream>>>(Bb, W2, b2, ab1, A, C);
    stats_partial<<<dim3(64, 32), 256, 0, stream>>>(A, partial, 0);
    stats_partial<<<dim3(64, 32), 256, 0, stream>>>(C, partial, 64);
    stats_final<<<128, 64, 0, stream>>>(partial, g2, be2, ab2, 128);
    final_max<<<B_ * S_, 128, 0, stream>>>(A, C, ab2, out);

    // conv2 branch (ft -> z2 in Bb)
    convk<32, false><<<dim3(R_ / 512, 1), 256, 0, stream>>>(ft, c2w, c2b, nullptr, Bb, nullptr);
    stats_partial<<<dim3(64, 32), 256, 0, stream>>>(Bb, partial, 0);
    stats_final<<<64, 64, 0, stream>>>(partial, bg2, bbe2, abz2, 64);

    // conv1 branch (ft{0,1,2,32} -> z1 in A; A free after final_max)
    conv1_kernel<<<R_ / 512, 256, 0, stream>>>(ft, c1w, c1b, A);
    stats_partial<<<dim3(64, 32), 256, 0, stream>>>(A, partial, 0);
    stats_final<<<64, 64, 0, stream>>>(partial, bg1, bbe1, abz1, 64);

    final_meanmax<<<B_ * S_, 128, 0, stream>>>(A, Bb, abz1, abz2, out);
}

// Round 2
// 1674.775 us; speedup vs baseline: 1.5135x; 1.5135x over previous
//
#include <hip/hip_runtime.h>
#include <cfloat>
#include <math.h>

constexpr int B_ = 8, N_ = 4096, S_ = 1024, NS_ = 32;
constexpr int R_ = B_ * S_ * NS_;          // 262144 rows (b,s,k)
constexpr float EPS_ = 1e-5f;

// ---------------------------------------------------------------- FPS
// One block per batch, 512 threads, 8 points each. Exact reference
// semantics: ct_idx[0]=0; dist=min(dist,d); argmax with first-index tie.
// Critical-path optimized: u64-packed (dist,~idx) max-reduce (2 shuffles/stage),
// single barrier per iteration (parity double-buffer), centroid coords via
// LDS broadcast read from a staged xyz copy.
__global__ __launch_bounds__(512) void fps_kernel(const float* __restrict__ xyz,
                                                  int* __restrict__ ct_idx) {
    int b = blockIdx.x;
    const float* xb = xyz + (size_t)b * 3 * N_;
    int t = threadIdx.x;
    __shared__ float sx[N_], sy[N_], sz[N_];
    __shared__ unsigned long long sb[2][8];
    for (int i = t; i < N_; i += 512) {
        sx[i] = xb[i];
        sy[i] = xb[N_ + i];
        sz[i] = xb[2 * N_ + i];
    }
    float px[8], py[8], pz[8], dist[8];
    unsigned inv_idx[8];
#pragma unroll
    for (int j = 0; j < 8; j++) {
        int n = j * 512 + t;
        px[j] = xb[n];
        py[j] = xb[N_ + n];
        pz[j] = xb[2 * N_ + n];
        dist[j] = 1e10f;
        inv_idx[j] = ~(unsigned)n;
    }
    __syncthreads();
    float cx = sx[0], cy = sy[0], cz = sz[0];
    int far = 0;
    for (int it = 0; it < S_; it++) {
        if (t == 0) ct_idx[b * S_ + it] = far;
        unsigned long long best = 0ull;
#pragma unroll
        for (int j = 0; j < 8; j++) {
            float dx = px[j] - cx, dy = py[j] - cy, dz = pz[j] - cz;
            float d = dx * dx + dy * dy + dz * dz;     // same expr as passing version
            dist[j] = fminf(dist[j], d);
            unsigned long long pk =
                ((unsigned long long)__float_as_uint(dist[j]) << 32) | inv_idx[j];
            best = pk > best ? pk : best;
        }
#pragma unroll
        for (int m = 1; m < 64; m <<= 1) {
            unsigned long long o = __shfl_xor(best, m);
            best = o > best ? o : best;
        }
        int p = it & 1;
        if ((t & 63) == 0) sb[p][t >> 6] = best;
        __syncthreads();
#pragma unroll
        for (int w = 0; w < 8; w++) {
            unsigned long long o = sb[p][w];
            best = o > best ? o : best;
        }
        far = (int)(~(unsigned)(best & 0xffffffffu));
        cx = sx[far]; cy = sy[far]; cz = sz[far];
        // no trailing barrier: next iter writes the OTHER parity buffer, and a
        // wave can only reach iter+2's write after all waves passed iter+1's
        // barrier, which postdates every read of this parity's buffer.
    }
}

// ---------------------------------------------------------------- kNN
// One block per (b,s): d2 to all 4096 points in registers (16/thread),
// 32 iterations of block-argmin with smaller-index tie-break (= lax.top_k set).
__global__ __launch_bounds__(256) void knn_kernel(const float* __restrict__ xyz,
                                                  const int* __restrict__ ct_idx,
                                                  int* __restrict__ gidx) {
    int bs = blockIdx.x;
    int b = bs >> 10;
    const float* xb = xyz + (size_t)b * 3 * N_;
    int ci = ct_idx[bs];
    float cx = xb[ci], cy = xb[N_ + ci], cz = xb[2 * N_ + ci];
    float cs = cx * cx + cy * cy + cz * cz;
    int t = threadIdx.x;
    float val[16];
#pragma unroll
    for (int j = 0; j < 16; j++) {
        int n = j * 256 + t;
        float x = xb[n], y = xb[N_ + n], z = xb[2 * N_ + n];
        float xn = x * x + y * y + z * z;
        float dot = cx * x + cy * y + cz * z;
        val[j] = cs + xn - 2.f * dot;           // reference formula order
    }
    __shared__ float sv[4];
    __shared__ int si[4];
    int out_base = bs * NS_;
    for (int iter = 0; iter < NS_; iter++) {
        float bv = FLT_MAX; int bi = 1 << 30;
#pragma unroll
        for (int j = 0; j < 16; j++) {
            if (val[j] < bv) { bv = val[j]; bi = j * 256 + t; }
        }
#pragma unroll
        for (int m = 1; m < 64; m <<= 1) {
            float ov = __shfl_xor(bv, m); int oi = __shfl_xor(bi, m);
            if (ov < bv || (ov == bv && oi < bi)) { bv = ov; bi = oi; }
        }
        if ((t & 63) == 0) { sv[t >> 6] = bv; si[t >> 6] = bi; }
        __syncthreads();
        bv = sv[0]; bi = si[0];
#pragma unroll
        for (int w = 1; w < 4; w++) {
            float ov = sv[w]; int oi = si[w];
            if (ov < bv || (ov == bv && oi < bi)) { bv = ov; bi = oi; }
        }
        if (t == 0) gidx[out_base + iter] = bi;
        if ((bi & 255) == t) val[bi >> 8] = FLT_MAX;   // mark selected
        __syncthreads();
    }
}

// ---------------------------------------------------------------- ct_p output
__global__ __launch_bounds__(256) void ctp_kernel(const float* __restrict__ xyz,
                                                  const int* __restrict__ ct_idx,
                                                  float* __restrict__ out) {
    int i = blockIdx.x * 256 + threadIdx.x;
    if (i >= B_ * 3 * S_) return;
    int b = i / (3 * S_);
    int rem = i - b * 3 * S_;
    int c = rem >> 10;
    int s = rem & (S_ - 1);
    int ci = ct_idx[b * S_ + s];
    out[i] = xyz[(size_t)b * 3 * N_ + (size_t)c * N_ + ci];
}

// ---------------------------------------------------------------- gather -> ft [33][R]
// ch 0-2: rel xyz; ch 3-31: points; ch 32: rd
__global__ __launch_bounds__(256) void gather_kernel(const float* __restrict__ xyz,
                                                     const float* __restrict__ pts,
                                                     const int* __restrict__ ct_idx,
                                                     const int* __restrict__ gidx,
                                                     float* __restrict__ ft) {
    int r = blockIdx.x * 256 + threadIdx.x;
    int b = r >> 15;
    int s = (r >> 5) & (S_ - 1);
    int g = gidx[r];
    int ci = ct_idx[b * S_ + s];
    const float* xb = xyz + (size_t)b * 3 * N_;
    float rx = xb[g] - xb[ci];
    float ry = xb[N_ + g] - xb[N_ + ci];
    float rz = xb[2 * N_ + g] - xb[2 * N_ + ci];
    ft[r] = rx;
    ft[(size_t)R_ + r] = ry;
    ft[(size_t)2 * R_ + r] = rz;
    float rd = sqrtf(fmaxf(rx * rx + ry * ry + rz * rz, 1e-12f));
    ft[(size_t)32 * R_ + r] = rd;
    const float* pb = pts + (size_t)b * 29 * N_;
#pragma unroll
    for (int c = 0; c < 29; c++) ft[(size_t)(3 + c) * R_ + r] = pb[(size_t)c * N_ + g];
}

// ---------------------------------------------------------------- conv1x1 (+optional input BN-affine+relu)
// 64 output channels per y-block; 2 rows per thread; weights broadcast from LDS.
template <int CIN, bool AFF>
__global__ __launch_bounds__(256) void convk(const float* __restrict__ xin,
                                             const float* __restrict__ W,
                                             const float* __restrict__ bias,
                                             const float* __restrict__ ab,
                                             float* __restrict__ out0,
                                             float* __restrict__ out1) {
    __shared__ float Ws[CIN][64];
    __shared__ float bs[64];
    __shared__ float as_[CIN], bbs[CIN];
    int oc0 = blockIdx.y * 64;
    for (int i = threadIdx.x; i < CIN * 64; i += 256) {
        int o = i & 63, c = i >> 6;
        Ws[c][o] = W[(size_t)(oc0 + o) * CIN + c];
    }
    if (threadIdx.x < 64) bs[threadIdx.x] = bias[oc0 + threadIdx.x];
    if (AFF) {
        for (int i = threadIdx.x; i < CIN; i += 256) { as_[i] = ab[i]; bbs[i] = ab[CIN + i]; }
    }
    __syncthreads();
    size_t r0 = (size_t)blockIdx.x * 512 + threadIdx.x;
    float acc0[64], acc1[64];
#pragma unroll
    for (int o = 0; o < 64; o++) { acc0[o] = 0.f; acc1[o] = 0.f; }
    for (int c = 0; c < CIN; c++) {
        float x0 = xin[(size_t)c * R_ + r0];
        float x1 = xin[(size_t)c * R_ + r0 + 256];
        if (AFF) {
            float a = as_[c], bb = bbs[c];
            x0 = fmaxf(fmaf(a, x0, bb), 0.f);
            x1 = fmaxf(fmaf(a, x1, bb), 0.f);
        }
#pragma unroll
        for (int o = 0; o < 64; o++) {
            float w = Ws[c][o];
            acc0[o] = fmaf(x0, w, acc0[o]);
            acc1[o] = fmaf(x1, w, acc1[o]);
        }
    }
    float* outp = blockIdx.y ? out1 : out0;
#pragma unroll
    for (int o = 0; o < 64; o++) {
        float bv = bs[o];
        outp[(size_t)o * R_ + r0] = acc0[o] + bv;
        outp[(size_t)o * R_ + r0 + 256] = acc1[o] + bv;
    }
}

// conv1 branch: 4 input channels = ft{0,1,2,32} (rel xyz + rd)
__global__ __launch_bounds__(256) void conv1_kernel(const float* __restrict__ ft,
                                                    const float* __restrict__ W,
                                                    const float* __restrict__ bias,
                                                    float* __restrict__ out) {
    __shared__ float Ws[4][64];
    __shared__ float bs[64];
    {
        int i = threadIdx.x;
        if (i < 256) { int o = i & 63, c = i >> 6; Ws[c][o] = W[o * 4 + c]; }
    }
    if (threadIdx.x < 64) bs[threadIdx.x] = bias[threadIdx.x];
    __syncthreads();
    size_t r0 = (size_t)blockIdx.x * 512 + threadIdx.x;
    float acc0[64], acc1[64];
#pragma unroll
    for (int o = 0; o < 64; o++) { acc0[o] = 0.f; acc1[o] = 0.f; }
    const int chs[4] = {0, 1, 2, 32};
#pragma unroll
    for (int c = 0; c < 4; c++) {
        int ch = chs[c];
        float x0 = ft[(size_t)ch * R_ + r0];
        float x1 = ft[(size_t)ch * R_ + r0 + 256];
#pragma unroll
        for (int o = 0; o < 64; o++) {
            float w = Ws[c][o];
            acc0[o] = fmaf(x0, w, acc0[o]);
            acc1[o] = fmaf(x1, w, acc1[o]);
        }
    }
#pragma unroll
    for (int o = 0; o < 64; o++) {
        float bv = bs[o];
        out[(size_t)o * R_ + r0] = acc0[o] + bv;
        out[(size_t)o * R_ + r0 + 256] = acc1[o] + bv;
    }
}

// ---------------------------------------------------------------- BN stats (deterministic 2-stage)
__global__ __launch_bounds__(256) void stats_partial(const float* __restrict__ y,
                                                     float* __restrict__ partial,
                                                     int cofs) {
    int c = blockIdx.x, p = blockIdx.y;
    const float* src = y + (size_t)c * R_ + (size_t)p * (R_ / 32);
    float s = 0.f, q = 0.f;
    for (int i = threadIdx.x; i < R_ / 32; i += 256) {
        float v = src[i];
        s += v;
        q = fmaf(v, v, q);
    }
#pragma unroll
    for (int m = 1; m < 64; m <<= 1) { s += __shfl_xor(s, m); q += __shfl_xor(q, m); }
    __shared__ float ls[4], lq[4];
    int w = threadIdx.x >> 6;
    if ((threadIdx.x & 63) == 0) { ls[w] = s; lq[w] = q; }
    __syncthreads();
    if (threadIdx.x == 0) {
        s = ls[0] + ls[1] + ls[2] + ls[3];
        q = lq[0] + lq[1] + lq[2] + lq[3];
        int idx = ((cofs + c) * 32 + p) * 2;
        partial[idx] = s;
        partial[idx + 1] = q;
    }
}

__global__ __launch_bounds__(64) void stats_final(const float* __restrict__ partial,
                                                  const float* __restrict__ g,
                                                  const float* __restrict__ be,
                                                  float* __restrict__ ab, int C) {
    int c = blockIdx.x, t = threadIdx.x;
    float s = 0.f, q = 0.f;
    if (t < 32) {
        int idx = (c * 32 + t) * 2;
        s = partial[idx];
        q = partial[idx + 1];
    }
#pragma unroll
    for (int m = 1; m < 32; m <<= 1) { s += __shfl_xor(s, m); q += __shfl_xor(q, m); }
    if (t == 0) {
        float inv = 1.0f / (float)R_;
        float mean = s * inv;
        float var = q * inv - mean * mean;
        float a = g[c] / sqrtf(var + EPS_);
        ab[c] = a;
        ab[C + c] = be[c] - mean * a;
    }
}

// ---------------------------------------------------------------- epilogues
__global__ __launch_bounds__(128) void final_max(const float* __restrict__ yA,
                                                 const float* __restrict__ yC,
                                                 const float* __restrict__ ab,
                                                 float* __restrict__ out) {
    int bs = blockIdx.x;
    int c = threadIdx.x;
    const float* src = (c < 64 ? yA + (size_t)c * R_ : yC + (size_t)(c - 64) * R_) + (size_t)bs * NS_;
    float a = ab[c], bb = ab[128 + c];
    const float4* s4 = reinterpret_cast<const float4*>(src);
    float m = -FLT_MAX;
#pragma unroll
    for (int i = 0; i < 8; i++) {
        float4 v = s4[i];
        m = fmaxf(m, fmaxf(fmaf(a, v.x, bb), 0.f));
        m = fmaxf(m, fmaxf(fmaf(a, v.y, bb), 0.f));
        m = fmaxf(m, fmaxf(fmaf(a, v.z, bb), 0.f));
        m = fmaxf(m, fmaxf(fmaf(a, v.w, bb), 0.f));
    }
    int b = bs >> 10, s = bs & (S_ - 1);
    out[24576 + (size_t)b * 393216 + (size_t)c * 1024 + s] = m;
}

__global__ __launch_bounds__(128) void final_meanmax(const float* __restrict__ z1,
                                                     const float* __restrict__ z2,
                                                     const float* __restrict__ ab1,
                                                     const float* __restrict__ ab2,
                                                     float* __restrict__ out) {
    int bs = blockIdx.x;
    int c = threadIdx.x;
    const float* src;
    float a, bb;
    if (c < 64) { src = z1 + (size_t)c * R_; a = ab1[c]; bb = ab1[64 + c]; }
    else        { src = z2 + (size_t)(c - 64) * R_; a = ab2[c - 64]; bb = ab2[64 + (c - 64)]; }
    src += (size_t)bs * NS_;
    const float4* s4 = reinterpret_cast<const float4*>(src);
    float m = -FLT_MAX, sm = 0.f;
#pragma unroll
    for (int i = 0; i < 8; i++) {
        float4 v = s4[i];
        float t0 = fmaxf(fmaf(a, v.x, bb), 0.f); sm += t0; m = fmaxf(m, t0);
        float t1 = fmaxf(fmaf(a, v.y, bb), 0.f); sm += t1; m = fmaxf(m, t1);
        float t2 = fmaxf(fmaf(a, v.z, bb), 0.f); sm += t2; m = fmaxf(m, t2);
        float t3 = fmaxf(fmaf(a, v.w, bb), 0.f); sm += t3; m = fmaxf(m, t3);
    }
    int b = bs >> 10, s = bs & (S_ - 1);
    size_t ob = 24576 + (size_t)b * 393216;
    out[ob + (size_t)(128 + c) * 1024 + s] = sm * 0.03125f;
    out[ob + (size_t)(256 + c) * 1024 + s] = m;
}

// ================================================================ launch
extern "C" void kernel_launch(void* const* d_in, const int* in_sizes, int n_in,
                              void* d_out, int out_size, void* d_ws, size_t ws_size,
                              hipStream_t stream) {
    const float* xyz = (const float*)d_in[0];
    const float* pts = (const float*)d_in[1];
    const float* W0 = (const float*)d_in[2];  const float* b0 = (const float*)d_in[3];
    const float* g0 = (const float*)d_in[4];  const float* be0 = (const float*)d_in[5];
    const float* W1 = (const float*)d_in[6];  const float* b1 = (const float*)d_in[7];
    const float* g1 = (const float*)d_in[8];  const float* be1 = (const float*)d_in[9];
    const float* W2 = (const float*)d_in[10]; const float* b2 = (const float*)d_in[11];
    const float* g2 = (const float*)d_in[12]; const float* be2 = (const float*)d_in[13];
    const float* c1w = (const float*)d_in[14]; const float* c1b = (const float*)d_in[15];
    const float* bg1 = (const float*)d_in[16]; const float* bbe1 = (const float*)d_in[17];
    const float* c2w = (const float*)d_in[18]; const float* c2b = (const float*)d_in[19];
    const float* bg2 = (const float*)d_in[20]; const float* bbe2 = (const float*)d_in[21];
    float* out = (float*)d_out;

    // workspace layout (floats after the two int arrays)
    int* ct_idx = (int*)d_ws;                       // [8192]
    int* gidx = ct_idx + B_ * S_;                   // [262144]
    float* fbase = (float*)d_ws;
    float* ft = fbase + 270336;                     // 33*R
    float* A = ft + (size_t)33 * R_;                // 64*R   (y0 -> y2.lo -> z1)
    float* Bb = A + (size_t)64 * R_;                // 64*R   (y1 -> z2)
    float* C = Bb + (size_t)64 * R_;                // 64*R   (y2.hi)
    float* partial = C + (size_t)64 * R_;           // 8192
    float* ab0 = partial + 8192;                    // 128
    float* ab1 = ab0 + 128;                         // 128
    float* ab2 = ab1 + 128;                         // 256
    float* abz1 = ab2 + 256;                        // 128
    float* abz2 = abz1 + 128;                       // 128

    fps_kernel<<<B_, 512, 0, stream>>>(xyz, ct_idx);
    knn_kernel<<<B_ * S_, 256, 0, stream>>>(xyz, ct_idx, gidx);
    ctp_kernel<<<(B_ * 3 * S_ + 255) / 256, 256, 0, stream>>>(xyz, ct_idx, out);
    gather_kernel<<<R_ / 256, 256, 0, stream>>>(xyz, pts, ct_idx, gidx, ft);

    // MLP stack
    convk<32, false><<<dim3(R_ / 512, 1), 256, 0, stream>>>(ft, W0, b0, nullptr, A, nullptr);
    stats_partial<<<dim3(64, 32), 256, 0, stream>>>(A, partial, 0);
    stats_final<<<64, 64, 0, stream>>>(partial, g0, be0, ab0, 64);
    convk<64, true><<<dim3(R_ / 512, 1), 256, 0, stream>>>(A, W1, b1, ab0, Bb, nullptr);
    stats_partial<<<dim3(64, 32), 256, 0, stream>>>(Bb, partial, 0);
    stats_final<<<64, 64, 0, stream>>>(partial, g1, be1, ab1, 64);
    convk<64, true><<<dim3(R_ / 512, 2), 256, 0, stream>>>(Bb, W2, b2, ab1, A, C);
    stats_partial<<<dim3(64, 32), 256, 0, stream>>>(A, partial, 0);
    stats_partial<<<dim3(64, 32), 256, 0, stream>>>(C, partial, 64);
    stats_final<<<128, 64, 0, stream>>>(partial, g2, be2, ab2, 128);
    final_max<<<B_ * S_, 128, 0, stream>>>(A, C, ab2, out);

    // conv2 branch (ft -> z2 in Bb)
    convk<32, false><<<dim3(R_ / 512, 1), 256, 0, stream>>>(ft, c2w, c2b, nullptr, Bb, nullptr);
    stats_partial<<<dim3(64, 32), 256, 0, stream>>>(Bb, partial, 0);
    stats_final<<<64, 64, 0, stream>>>(partial, bg2, bbe2, abz2, 64);

    // conv1 branch (ft{0,1,2,32} -> z1 in A; A free after final_max)
    conv1_kernel<<<R_ / 512, 256, 0, stream>>>(ft, c1w, c1b, A);
    stats_partial<<<dim3(64, 32), 256, 0, stream>>>(A, partial, 0);
    stats_final<<<64, 64, 0, stream>>>(partial, bg1, bbe1, abz1, 64);

    final_meanmax<<<B_ * S_, 128, 0, stream>>>(A, Bb, abz1, abz2, out);
}

// Round 3
// 1429.840 us; speedup vs baseline: 1.7727x; 1.1713x over previous
//
#include <hip/hip_runtime.h>
#include <cfloat>
#include <math.h>

constexpr int B_ = 8, N_ = 4096, S_ = 1024, NS_ = 32;
constexpr int R_ = B_ * S_ * NS_;          // 262144 rows (b,s,k)
constexpr float EPS_ = 1e-5f;

// DPP wave-64 reductions: result valid in lane 63 (other lanes partial).
// Sequence: row_shr 1/2/4/8 within 16-lane rows, then bcast15, bcast31.
__device__ __forceinline__ unsigned dpp_red_umax(unsigned x) {
    unsigned t;
#define STEP_(ctrl) t = (unsigned)__builtin_amdgcn_update_dpp((int)x, (int)x, ctrl, 0xf, 0xf, false); x = x > t ? x : t;
    STEP_(0x111) STEP_(0x112) STEP_(0x114) STEP_(0x118) STEP_(0x142) STEP_(0x143)
#undef STEP_
    return x;
}
__device__ __forceinline__ unsigned dpp_red_umin(unsigned x) {
    unsigned t;
#define STEP_(ctrl) t = (unsigned)__builtin_amdgcn_update_dpp((int)x, (int)x, ctrl, 0xf, 0xf, false); x = x < t ? x : t;
    STEP_(0x111) STEP_(0x112) STEP_(0x114) STEP_(0x118) STEP_(0x142) STEP_(0x143)
#undef STEP_
    return x;
}

// ---------------------------------------------------------------- FPS
// One block per batch, 256 threads x 16 points. Exact reference semantics:
// ct_idx[0]=0; dist=min(dist,d); argmax with first-index tie-break.
// Per-iter reduce: balanced fmax tree (reg) -> 6-op DPP u32 max -> readlane
// -> bitwise-match index -> umin tree -> 6-op DPP u32 min -> 4-entry LDS
// combine (packed u64, parity double-buffered, single barrier).
__global__ __launch_bounds__(256) void fps_kernel(const float* __restrict__ xyz,
                                                  int* __restrict__ ct_idx) {
    int b = blockIdx.x;
    const float* xb = xyz + (size_t)b * 3 * N_;
    int t = threadIdx.x;
    __shared__ float sx[N_], sy[N_], sz[N_];
    __shared__ unsigned long long sb[2][4];
    for (int i = t; i < N_; i += 256) {
        sx[i] = xb[i];
        sy[i] = xb[N_ + i];
        sz[i] = xb[2 * N_ + i];
    }
    float px[16], py[16], pz[16], dist[16];
#pragma unroll
    for (int j = 0; j < 16; j++) {
        int n = j * 256 + t;
        px[j] = xb[n];
        py[j] = xb[N_ + n];
        pz[j] = xb[2 * N_ + n];
        dist[j] = 1e10f;
    }
    __syncthreads();
    float cx = sx[0], cy = sy[0], cz = sz[0];
    int far = 0;
    int w = t >> 6;
    for (int it = 0; it < S_; it++) {
        if (t == 0) ct_idx[b * S_ + it] = far;
#pragma unroll
        for (int j = 0; j < 16; j++) {
            float dx = px[j] - cx, dy = py[j] - cy, dz = pz[j] - cz;
            float d = dx * dx;
            d = fmaf(dy, dy, d);
            d = fmaf(dz, dz, d);                  // same value chain as passing version
            dist[j] = fminf(dist[j], d);
        }
        // balanced fmax tree over the 16 local dists
        float m8[8], m4[4];
#pragma unroll
        for (int j = 0; j < 8; j++) m8[j] = fmaxf(dist[2 * j], dist[2 * j + 1]);
#pragma unroll
        for (int j = 0; j < 4; j++) m4[j] = fmaxf(m8[2 * j], m8[2 * j + 1]);
        float lmax = fmaxf(fmaxf(m4[0], m4[1]), fmaxf(m4[2], m4[3]));
        // wave max (nonneg f32 bits order as u32)
        unsigned wmax = (unsigned)__builtin_amdgcn_readlane(
            (int)dpp_red_umax(__float_as_uint(lmax)), 63);
        // smallest n in this wave achieving wmax (bitwise-exact match)
        unsigned c8[8], c4[4];
#pragma unroll
        for (int j = 0; j < 8; j++) {
            unsigned a = (__float_as_uint(dist[2 * j]) == wmax)
                             ? (unsigned)((2 * j) * 256 + t) : 0xffffffffu;
            unsigned bq = (__float_as_uint(dist[2 * j + 1]) == wmax)
                             ? (unsigned)((2 * j + 1) * 256 + t) : 0xffffffffu;
            c8[j] = a < bq ? a : bq;
        }
#pragma unroll
        for (int j = 0; j < 4; j++) c4[j] = c8[2 * j] < c8[2 * j + 1] ? c8[2 * j] : c8[2 * j + 1];
        unsigned c01 = c4[0] < c4[1] ? c4[0] : c4[1];
        unsigned c23 = c4[2] < c4[3] ? c4[2] : c4[3];
        unsigned mn = dpp_red_umin(c01 < c23 ? c01 : c23);
        int p = it & 1;
        if ((t & 63) == 63)
            sb[p][w] = ((unsigned long long)wmax << 32) | (unsigned)(~mn);
        __syncthreads();
        unsigned long long b0 = sb[p][0], b1 = sb[p][1], b2 = sb[p][2], b3 = sb[p][3];
        unsigned long long m01 = b0 > b1 ? b0 : b1;
        unsigned long long m23 = b2 > b3 ? b2 : b3;
        unsigned long long best = m01 > m23 ? m01 : m23;
        far = (int)(~(unsigned)(best & 0xffffffffu));
        cx = sx[far]; cy = sy[far]; cz = sz[far];
        // no trailing barrier: next iter writes the OTHER parity buffer; a wave
        // reaches iter+2's write only after all waves passed iter+1's barrier,
        // which postdates every read of this parity's buffer.
    }
}

// ---------------------------------------------------------------- kNN
// One block per (b,s): d2 to all 4096 points in registers (16/thread),
// 32 iterations of block-argmin with smaller-index tie-break (= lax.top_k set).
__global__ __launch_bounds__(256) void knn_kernel(const float* __restrict__ xyz,
                                                  const int* __restrict__ ct_idx,
                                                  int* __restrict__ gidx) {
    int bs = blockIdx.x;
    int b = bs >> 10;
    const float* xb = xyz + (size_t)b * 3 * N_;
    int ci = ct_idx[bs];
    float cx = xb[ci], cy = xb[N_ + ci], cz = xb[2 * N_ + ci];
    float cs = cx * cx + cy * cy + cz * cz;
    int t = threadIdx.x;
    float val[16];
#pragma unroll
    for (int j = 0; j < 16; j++) {
        int n = j * 256 + t;
        float x = xb[n], y = xb[N_ + n], z = xb[2 * N_ + n];
        float xn = x * x + y * y + z * z;
        float dot = cx * x + cy * y + cz * z;
        val[j] = cs + xn - 2.f * dot;           // reference formula order
    }
    __shared__ float sv[4];
    __shared__ int si[4];
    int out_base = bs * NS_;
    for (int iter = 0; iter < NS_; iter++) {
        float bv = FLT_MAX; int bi = 1 << 30;
#pragma unroll
        for (int j = 0; j < 16; j++) {
            if (val[j] < bv) { bv = val[j]; bi = j * 256 + t; }
        }
#pragma unroll
        for (int m = 1; m < 64; m <<= 1) {
            float ov = __shfl_xor(bv, m); int oi = __shfl_xor(bi, m);
            if (ov < bv || (ov == bv && oi < bi)) { bv = ov; bi = oi; }
        }
        if ((t & 63) == 0) { sv[t >> 6] = bv; si[t >> 6] = bi; }
        __syncthreads();
        bv = sv[0]; bi = si[0];
#pragma unroll
        for (int w = 1; w < 4; w++) {
            float ov = sv[w]; int oi = si[w];
            if (ov < bv || (ov == bv && oi < bi)) { bv = ov; bi = oi; }
        }
        if (t == 0) gidx[out_base + iter] = bi;
        if ((bi & 255) == t) val[bi >> 8] = FLT_MAX;   // mark selected
        __syncthreads();
    }
}

// ---------------------------------------------------------------- ct_p output
__global__ __launch_bounds__(256) void ctp_kernel(const float* __restrict__ xyz,
                                                  const int* __restrict__ ct_idx,
                                                  float* __restrict__ out) {
    int i = blockIdx.x * 256 + threadIdx.x;
    if (i >= B_ * 3 * S_) return;
    int b = i / (3 * S_);
    int rem = i - b * 3 * S_;
    int c = rem >> 10;
    int s = rem & (S_ - 1);
    int ci = ct_idx[b * S_ + s];
    out[i] = xyz[(size_t)b * 3 * N_ + (size_t)c * N_ + ci];
}

// ---------------------------------------------------------------- gather -> ft [33][R]
// ch 0-2: rel xyz; ch 3-31: points; ch 32: rd
__global__ __launch_bounds__(256) void gather_kernel(const float* __restrict__ xyz,
                                                     const float* __restrict__ pts,
                                                     const int* __restrict__ ct_idx,
                                                     const int* __restrict__ gidx,
                                                     float* __restrict__ ft) {
    int r = blockIdx.x * 256 + threadIdx.x;
    int b = r >> 15;
    int s = (r >> 5) & (S_ - 1);
    int g = gidx[r];
    int ci = ct_idx[b * S_ + s];
    const float* xb = xyz + (size_t)b * 3 * N_;
    float rx = xb[g] - xb[ci];
    float ry = xb[N_ + g] - xb[N_ + ci];
    float rz = xb[2 * N_ + g] - xb[2 * N_ + ci];
    ft[r] = rx;
    ft[(size_t)R_ + r] = ry;
    ft[(size_t)2 * R_ + r] = rz;
    float rd = sqrtf(fmaxf(rx * rx + ry * ry + rz * rz, 1e-12f));
    ft[(size_t)32 * R_ + r] = rd;
    const float* pb = pts + (size_t)b * 29 * N_;
#pragma unroll
    for (int c = 0; c < 29; c++) ft[(size_t)(3 + c) * R_ + r] = pb[(size_t)c * N_ + g];
}

// ---------------------------------------------------------------- conv1x1 (+optional input BN-affine+relu)
// 64 output channels per y-block; 2 rows per thread; weights broadcast from LDS.
template <int CIN, bool AFF>
__global__ __launch_bounds__(256) void convk(const float* __restrict__ xin,
                                             const float* __restrict__ W,
                                             const float* __restrict__ bias,
                                             const float* __restrict__ ab,
                                             float* __restrict__ out0,
                                             float* __restrict__ out1) {
    __shared__ float Ws[CIN][64];
    __shared__ float bs[64];
    __shared__ float as_[CIN], bbs[CIN];
    int oc0 = blockIdx.y * 64;
    for (int i = threadIdx.x; i < CIN * 64; i += 256) {
        int o = i & 63, c = i >> 6;
        Ws[c][o] = W[(size_t)(oc0 + o) * CIN + c];
    }
    if (threadIdx.x < 64) bs[threadIdx.x] = bias[oc0 + threadIdx.x];
    if (AFF) {
        for (int i = threadIdx.x; i < CIN; i += 256) { as_[i] = ab[i]; bbs[i] = ab[CIN + i]; }
    }
    __syncthreads();
    size_t r0 = (size_t)blockIdx.x * 512 + threadIdx.x;
    float acc0[64], acc1[64];
#pragma unroll
    for (int o = 0; o < 64; o++) { acc0[o] = 0.f; acc1[o] = 0.f; }
    for (int c = 0; c < CIN; c++) {
        float x0 = xin[(size_t)c * R_ + r0];
        float x1 = xin[(size_t)c * R_ + r0 + 256];
        if (AFF) {
            float a = as_[c], bb = bbs[c];
            x0 = fmaxf(fmaf(a, x0, bb), 0.f);
            x1 = fmaxf(fmaf(a, x1, bb), 0.f);
        }
#pragma unroll
        for (int o = 0; o < 64; o++) {
            float w = Ws[c][o];
            acc0[o] = fmaf(x0, w, acc0[o]);
            acc1[o] = fmaf(x1, w, acc1[o]);
        }
    }
    float* outp = blockIdx.y ? out1 : out0;
#pragma unroll
    for (int o = 0; o < 64; o++) {
        float bv = bs[o];
        outp[(size_t)o * R_ + r0] = acc0[o] + bv;
        outp[(size_t)o * R_ + r0 + 256] = acc1[o] + bv;
    }
}

// conv1 branch: 4 input channels = ft{0,1,2,32} (rel xyz + rd)
__global__ __launch_bounds__(256) void conv1_kernel(const float* __restrict__ ft,
                                                    const float* __restrict__ W,
                                                    const float* __restrict__ bias,
                                                    float* __restrict__ out) {
    __shared__ float Ws[4][64];
    __shared__ float bs[64];
    {
        int i = threadIdx.x;
        if (i < 256) { int o = i & 63, c = i >> 6; Ws[c][o] = W[o * 4 + c]; }
    }
    if (threadIdx.x < 64) bs[threadIdx.x] = bias[threadIdx.x];
    __syncthreads();
    size_t r0 = (size_t)blockIdx.x * 512 + threadIdx.x;
    float acc0[64], acc1[64];
#pragma unroll
    for (int o = 0; o < 64; o++) { acc0[o] = 0.f; acc1[o] = 0.f; }
    const int chs[4] = {0, 1, 2, 32};
#pragma unroll
    for (int c = 0; c < 4; c++) {
        int ch = chs[c];
        float x0 = ft[(size_t)ch * R_ + r0];
        float x1 = ft[(size_t)ch * R_ + r0 + 256];
#pragma unroll
        for (int o = 0; o < 64; o++) {
            float w = Ws[c][o];
            acc0[o] = fmaf(x0, w, acc0[o]);
            acc1[o] = fmaf(x1, w, acc1[o]);
        }
    }
#pragma unroll
    for (int o = 0; o < 64; o++) {
        float bv = bs[o];
        out[(size_t)o * R_ + r0] = acc0[o] + bv;
        out[(size_t)o * R_ + r0 + 256] = acc1[o] + bv;
    }
}

// ---------------------------------------------------------------- BN stats (deterministic 2-stage)
__global__ __launch_bounds__(256) void stats_partial(const float* __restrict__ y,
                                                     float* __restrict__ partial,
                                                     int cofs) {
    int c = blockIdx.x, p = blockIdx.y;
    const float* src = y + (size_t)c * R_ + (size_t)p * (R_ / 32);
    float s = 0.f, q = 0.f;
    for (int i = threadIdx.x; i < R_ / 32; i += 256) {
        float v = src[i];
        s += v;
        q = fmaf(v, v, q);
    }
#pragma unroll
    for (int m = 1; m < 64; m <<= 1) { s += __shfl_xor(s, m); q += __shfl_xor(q, m); }
    __shared__ float ls[4], lq[4];
    int w = threadIdx.x >> 6;
    if ((threadIdx.x & 63) == 0) { ls[w] = s; lq[w] = q; }
    __syncthreads();
    if (threadIdx.x == 0) {
        s = ls[0] + ls[1] + ls[2] + ls[3];
        q = lq[0] + lq[1] + lq[2] + lq[3];
        int idx = ((cofs + c) * 32 + p) * 2;
        partial[idx] = s;
        partial[idx + 1] = q;
    }
}

__global__ __launch_bounds__(64) void stats_final(const float* __restrict__ partial,
                                                  const float* __restrict__ g,
                                                  const float* __restrict__ be,
                                                  float* __restrict__ ab, int C) {
    int c = blockIdx.x, t = threadIdx.x;
    float s = 0.f, q = 0.f;
    if (t < 32) {
        int idx = (c * 32 + t) * 2;
        s = partial[idx];
        q = partial[idx + 1];
    }
#pragma unroll
    for (int m = 1; m < 32; m <<= 1) { s += __shfl_xor(s, m); q += __shfl_xor(q, m); }
    if (t == 0) {
        float inv = 1.0f / (float)R_;
        float mean = s * inv;
        float var = q * inv - mean * mean;
        float a = g[c] / sqrtf(var + EPS_);
        ab[c] = a;
        ab[C + c] = be[c] - mean * a;
    }
}

// ---------------------------------------------------------------- epilogues
__global__ __launch_bounds__(128) void final_max(const float* __restrict__ yA,
                                                 const float* __restrict__ yC,
                                                 const float* __restrict__ ab,
                                                 float* __restrict__ out) {
    int bs = blockIdx.x;
    int c = threadIdx.x;
    const float* src = (c < 64 ? yA + (size_t)c * R_ : yC + (size_t)(c - 64) * R_) + (size_t)bs * NS_;
    float a = ab[c], bb = ab[128 + c];
    const float4* s4 = reinterpret_cast<const float4*>(src);
    float m = -FLT_MAX;
#pragma unroll
    for (int i = 0; i < 8; i++) {
        float4 v = s4[i];
        m = fmaxf(m, fmaxf(fmaf(a, v.x, bb), 0.f));
        m = fmaxf(m, fmaxf(fmaf(a, v.y, bb), 0.f));
        m = fmaxf(m, fmaxf(fmaf(a, v.z, bb), 0.f));
        m = fmaxf(m, fmaxf(fmaf(a, v.w, bb), 0.f));
    }
    int b = bs >> 10, s = bs & (S_ - 1);
    out[24576 + (size_t)b * 393216 + (size_t)c * 1024 + s] = m;
}

__global__ __launch_bounds__(128) void final_meanmax(const float* __restrict__ z1,
                                                     const float* __restrict__ z2,
                                                     const float* __restrict__ ab1,
                                                     const float* __restrict__ ab2,
                                                     float* __restrict__ out) {
    int bs = blockIdx.x;
    int c = threadIdx.x;
    const float* src;
    float a, bb;
    if (c < 64) { src = z1 + (size_t)c * R_; a = ab1[c]; bb = ab1[64 + c]; }
    else        { src = z2 + (size_t)(c - 64) * R_; a = ab2[c - 64]; bb = ab2[64 + (c - 64)]; }
    src += (size_t)bs * NS_;
    const float4* s4 = reinterpret_cast<const float4*>(src);
    float m = -FLT_MAX, sm = 0.f;
#pragma unroll
    for (int i = 0; i < 8; i++) {
        float4 v = s4[i];
        float t0 = fmaxf(fmaf(a, v.x, bb), 0.f); sm += t0; m = fmaxf(m, t0);
        float t1 = fmaxf(fmaf(a, v.y, bb), 0.f); sm += t1; m = fmaxf(m, t1);
        float t2 = fmaxf(fmaf(a, v.z, bb), 0.f); sm += t2; m = fmaxf(m, t2);
        float t3 = fmaxf(fmaf(a, v.w, bb), 0.f); sm += t3; m = fmaxf(m, t3);
    }
    int b = bs >> 10, s = bs & (S_ - 1);
    size_t ob = 24576 + (size_t)b * 393216;
    out[ob + (size_t)(128 + c) * 1024 + s] = sm * 0.03125f;
    out[ob + (size_t)(256 + c) * 1024 + s] = m;
}

// ================================================================ launch
extern "C" void kernel_launch(void* const* d_in, const int* in_sizes, int n_in,
                              void* d_out, int out_size, void* d_ws, size_t ws_size,
                              hipStream_t stream) {
    const float* xyz = (const float*)d_in[0];
    const float* pts = (const float*)d_in[1];
    const float* W0 = (const float*)d_in[2];  const float* b0 = (const float*)d_in[3];
    const float* g0 = (const float*)d_in[4];  const float* be0 = (const float*)d_in[5];
    const float* W1 = (const float*)d_in[6];  const float* b1 = (const float*)d_in[7];
    const float* g1 = (const float*)d_in[8];  const float* be1 = (const float*)d_in[9];
    const float* W2 = (const float*)d_in[10]; const float* b2 = (const float*)d_in[11];
    const float* g2 = (const float*)d_in[12]; const float* be2 = (const float*)d_in[13];
    const float* c1w = (const float*)d_in[14]; const float* c1b = (const float*)d_in[15];
    const float* bg1 = (const float*)d_in[16]; const float* bbe1 = (const float*)d_in[17];
    const float* c2w = (const float*)d_in[18]; const float* c2b = (const float*)d_in[19];
    const float* bg2 = (const float*)d_in[20]; const float* bbe2 = (const float*)d_in[21];
    float* out = (float*)d_out;

    // workspace layout (floats after the two int arrays)
    int* ct_idx = (int*)d_ws;                       // [8192]
    int* gidx = ct_idx + B_ * S_;                   // [262144]
    float* fbase = (float*)d_ws;
    float* ft = fbase + 270336;                     // 33*R
    float* A = ft + (size_t)33 * R_;                // 64*R   (y0 -> y2.lo -> z1)
    float* Bb = A + (size_t)64 * R_;                // 64*R   (y1 -> z2)
    float* C = Bb + (size_t)64 * R_;                // 64*R   (y2.hi)
    float* partial = C + (size_t)64 * R_;           // 8192
    float* ab0 = partial + 8192;                    // 128
    float* ab1 = ab0 + 128;                         // 128
    float* ab2 = ab1 + 128;                         // 256
    float* abz1 = ab2 + 256;                        // 128
    float* abz2 = abz1 + 128;                       // 128

    fps_kernel<<<B_, 256, 0, stream>>>(xyz, ct_idx);
    knn_kernel<<<B_ * S_, 256, 0, stream>>>(xyz, ct_idx, gidx);
    ctp_kernel<<<(B_ * 3 * S_ + 255) / 256, 256, 0, stream>>>(xyz, ct_idx, out);
    gather_kernel<<<R_ / 256, 256, 0, stream>>>(xyz, pts, ct_idx, gidx, ft);

    // MLP stack
    convk<32, false><<<dim3(R_ / 512, 1), 256, 0, stream>>>(ft, W0, b0, nullptr, A, nullptr);
    stats_partial<<<dim3(64, 32), 256, 0, stream>>>(A, partial, 0);
    stats_final<<<64, 64, 0, stream>>>(partial, g0, be0, ab0, 64);
    convk<64, true><<<dim3(R_ / 512, 1), 256, 0, stream>>>(A, W1, b1, ab0, Bb, nullptr);
    stats_partial<<<dim3(64, 32), 256, 0, stream>>>(Bb, partial, 0);
    stats_final<<<64, 64, 0, stream>>>(partial, g1, be1, ab1, 64);
    convk<64, true><<<dim3(R_ / 512, 2), 256, 0, stream>>>(Bb, W2, b2, ab1, A, C);
    stats_partial<<<dim3(64, 32), 256, 0, stream>>>(A, partial, 0);
    stats_partial<<<dim3(64, 32), 256, 0, stream>>>(C, partial, 64);
    stats_final<<<128, 64, 0, stream>>>(partial, g2, be2, ab2, 128);
    final_max<<<B_ * S_, 128, 0, stream>>>(A, C, ab2, out);

    // conv2 branch (ft -> z2 in Bb)
    convk<32, false><<<dim3(R_ / 512, 1), 256, 0, stream>>>(ft, c2w, c2b, nullptr, Bb, nullptr);
    stats_partial<<<dim3(64, 32), 256, 0, stream>>>(Bb, partial, 0);
    stats_final<<<64, 64, 0, stream>>>(partial, bg2, bbe2, abz2, 64);

    // conv1 branch (ft{0,1,2,32} -> z1 in A; A free after final_max)
    conv1_kernel<<<R_ / 512, 256, 0, stream>>>(ft, c1w, c1b, A);
    stats_partial<<<dim3(64, 32), 256, 0, stream>>>(A, partial, 0);
    stats_final<<<64, 64, 0, stream>>>(partial, bg1, bbe1, abz1, 64);

    final_meanmax<<<B_ * S_, 128, 0, stream>>>(A, Bb, abz1, abz2, out);
}